// Round 9
// baseline (412.253 us; speedup 1.0000x reference)
//
#include <hip/hip_runtime.h>

#define BATCH 16
#define PS 784          // nodes per partition; LDS acc = 784*17*4 = 53312 B
#define STRIDE 17       // padded per-node LDS stride (floats)
#define NPART 64        // 64*784 = 50176 >= 50001
#define PAIRS (NPART * NPART)   // 4096 (owner, remote) bins
#define SLICES 8        // accumulate blocks per partition
#define NB (NPART * SLICES)    // 512 accumulate blocks
#define SB 128          // hist/scatter blocks
#define TPB 1024

typedef unsigned int uint4v __attribute__((ext_vector_type(4)));

// fast tanh: 1 - 2/(e^{2z}+1); rel err ~1e-6 vs 2.6e-4 threshold
static __device__ __forceinline__ float fast_tanh(float z) {
    float ez = __expf(2.0f * z);
    return 1.0f - 2.0f * __builtin_amdgcn_rcpf(ez + 1.0f);
}

// aux_T[(N+1)][16]: node-major transpose of x with a zero row at node 0.
__global__ void build_aux_T(const float* __restrict__ x, float* __restrict__ auxT, int n) {
    int idx = blockIdx.x * blockDim.x + threadIdx.x;
    if (idx >= BATCH * n) return;
    int b = idx / n;
    int i = idx % n;
    auxT[(i + 1) * BATCH + b] = x[idx];
    if (idx < BATCH) auxT[idx] = 0.0f;
}

// ---------------- pair-binned sorted-record path ----------------

// Histogram of (owner,remote) pair bins. hist[SB][PAIRS].
__global__ __launch_bounds__(TPB)
void pair_hist(const int* __restrict__ src, const int* __restrict__ des,
               unsigned* __restrict__ hist, int E) {
    __shared__ unsigned h[PAIRS];
    int tid = threadIdx.x;
    for (int i = tid; i < PAIRS; i += TPB) h[i] = 0;
    __syncthreads();
    long t = (long)blockIdx.x * TPB + tid;
    long stride = (long)gridDim.x * TPB * 4;
    for (long e0 = t * 4; e0 < E; e0 += stride) {
        int ne = (int)min((long)4, (long)E - e0);
        if (ne == 4) {
            int4 sv = *(const int4*)(src + e0);
            int4 dv = *(const int4*)(des + e0);
            int ss[4] = {sv.x, sv.y, sv.z, sv.w};
            int dd[4] = {dv.x, dv.y, dv.z, dv.w};
#pragma unroll
            for (int j = 0; j < 4; ++j) {
                int ps = ss[j] / PS, pd = dd[j] / PS;
                atomicAdd(&h[ps * NPART + pd], 1u);
                if (pd != ps) atomicAdd(&h[pd * NPART + ps], 1u);
            }
        } else {
            for (int j = 0; j < ne; ++j) {
                int ps = src[e0 + j] / PS, pd = des[e0 + j] / PS;
                atomicAdd(&h[ps * NPART + pd], 1u);
                if (pd != ps) atomicAdd(&h[pd * NPART + ps], 1u);
            }
        }
    }
    __syncthreads();
    for (int i = tid; i < PAIRS; i += TPB)
        hist[(size_t)blockIdx.x * PAIRS + i] = h[i];
}

// Per-bin totals: 64 bins per block x 16 threads. Grid = PAIRS/64.
__global__ __launch_bounds__(TPB)
void totals_kernel(const unsigned* __restrict__ hist, unsigned* __restrict__ binTotal) {
    int tid = threadIdx.x;
    int bin = blockIdx.x * 64 + (tid >> 4);
    int j = tid & 15;
    unsigned s = 0;
    for (int r = j; r < SB; r += 16) s += hist[(size_t)r * PAIRS + bin];
#pragma unroll
    for (int m = 1; m < 16; m <<= 1) s += __shfl_xor(s, m, 64);
    if (j == 0) binTotal[bin] = s;
}

// Single block: exclusive scan of binTotal[PAIRS] -> binStart; owner aggregates.
__global__ __launch_bounds__(1024)
void scan_totals(const unsigned* __restrict__ binTotal, unsigned* __restrict__ binStart,
                 unsigned* __restrict__ ownerStart, unsigned* __restrict__ ownerTotal) {
    __shared__ unsigned wsum[16];
    __shared__ unsigned oStart[NPART + 1];
    int tid = threadIdx.x;
    int lane = tid & 63;
    unsigned v[4];
    unsigned s = 0;
#pragma unroll
    for (int k = 0; k < 4; ++k) { v[k] = binTotal[tid * 4 + k]; s += v[k]; }
    unsigned inc = s;
    for (int off = 1; off < 64; off <<= 1) {
        unsigned t = __shfl_up(inc, off, 64);
        if (lane >= off) inc += t;
    }
    if (lane == 63) wsum[tid >> 6] = inc;
    __syncthreads();
    if (tid < 16) {
        unsigned w = wsum[tid];
        unsigned winc = w;
        for (int off = 1; off < 16; off <<= 1) {
            unsigned t = __shfl_up(winc, off, 64);
            if (tid >= off) winc += t;
        }
        wsum[tid] = winc - w;   // exclusive wave offset
    }
    __syncthreads();
    unsigned excl = (inc - s) + wsum[tid >> 6];
    unsigned run = excl;
#pragma unroll
    for (int k = 0; k < 4; ++k) { binStart[tid * 4 + k] = run; run += v[k]; }
    if ((tid & 15) == 0) oStart[tid >> 4] = excl;   // bin (tid/16)*64 boundary
    if (tid == 1023) oStart[NPART] = excl + s;      // grand total
    __syncthreads();
    if (tid < NPART) {
        ownerStart[tid] = oStart[tid];
        ownerTotal[tid] = oStart[tid + 1] - oStart[tid];
    }
}

// In-place hist -> per-(block,bin) scatter offsets. Grid = PAIRS/64.
__global__ __launch_bounds__(TPB)
void offsets_kernel(unsigned* __restrict__ hist, const unsigned* __restrict__ binStart) {
    int tid = threadIdx.x;
    int binLocal = tid >> 4;
    int bin = blockIdx.x * 64 + binLocal;
    int j = tid & 15;
    const int per = SB / 16;   // 8 contiguous rows per thread
    unsigned cs = 0;
    for (int r = j * per; r < (j + 1) * per; ++r) cs += hist[(size_t)r * PAIRS + bin];
    int waveBase = (binLocal & 3) * 16;
    unsigned excl = 0;
    for (int k = 0; k < 16; ++k) {
        unsigned vv = __shfl(cs, waveBase + k, 64);
        if (k < j) excl += vv;
    }
    unsigned run = binStart[bin] + excl;
    for (int r = j * per; r < (j + 1) * per; ++r) {
        unsigned t = hist[(size_t)r * PAIRS + bin];
        hist[(size_t)r * PAIRS + bin] = run;
        run += t;
    }
}

// Emit 16B records into (owner,remote) pair bins (2 records if cross-partition).
__global__ __launch_bounds__(TPB)
void scatter_pair(const int* __restrict__ src, const int* __restrict__ des,
                  const float* __restrict__ param, const unsigned* __restrict__ offsets,
                  uint4* __restrict__ records, int E) {
    __shared__ unsigned offs[PAIRS];
    int tid = threadIdx.x;
    for (int i = tid; i < PAIRS; i += TPB)
        offs[i] = offsets[(size_t)blockIdx.x * PAIRS + i];
    __syncthreads();
    long t = (long)blockIdx.x * TPB + tid;
    long stride = (long)gridDim.x * TPB * 4;
    for (long e0 = t * 4; e0 < E; e0 += stride) {
        int ne = (int)min((long)4, (long)E - e0);
        int ss[4], dd[4];
        float aa[4], ww[4], cc[4];
        if (ne == 4) {
            int4 sv = *(const int4*)(src + e0);
            int4 dv = *(const int4*)(des + e0);
            float4 av = *(const float4*)(param + e0);
            float4 wv = *(const float4*)(param + E + e0);
            float4 cv = *(const float4*)(param + 2 * (size_t)E + e0);
            ss[0]=sv.x; ss[1]=sv.y; ss[2]=sv.z; ss[3]=sv.w;
            dd[0]=dv.x; dd[1]=dv.y; dd[2]=dv.z; dd[3]=dv.w;
            aa[0]=av.x; aa[1]=av.y; aa[2]=av.z; aa[3]=av.w;
            ww[0]=wv.x; ww[1]=wv.y; ww[2]=wv.z; ww[3]=wv.w;
            cc[0]=cv.x; cc[1]=cv.y; cc[2]=cv.z; cc[3]=cv.w;
        } else {
            for (int j = 0; j < ne; ++j) {
                ss[j] = src[e0 + j]; dd[j] = des[e0 + j];
                aa[j] = param[e0 + j]; ww[j] = param[E + e0 + j];
                cc[j] = param[2 * (size_t)E + e0 + j];
            }
        }
        for (int j = 0; j < ne; ++j) {
            int s = ss[j], d = dd[j];
            uint4 rec = make_uint4((unsigned)s | ((unsigned)d << 16),
                                   __float_as_uint(aa[j]), __float_as_uint(ww[j]),
                                   __float_as_uint(cc[j]));
            int ps = s / PS, pd = d / PS;
            unsigned slot = atomicAdd(&offs[ps * NPART + pd], 1u);
            records[slot] = rec;
            if (pd != ps) {
                unsigned slot2 = atomicAdd(&offs[pd * NPART + ps], 1u);
                records[slot2] = rec;
            }
        }
    }
}

// Block (p, slice): 4 lanes per record, lane owns 4 batches. Records arrive
// sorted by remote partition -> both gather windows are ~50KB (L1/L2-hot).
__global__ __launch_bounds__(TPB, 8)
void accumulate_kernel(const uint4* __restrict__ records, const float* __restrict__ auxT,
                       const unsigned* __restrict__ binStart,
                       const unsigned* __restrict__ binTotal,
                       float* __restrict__ partials) {
    __shared__ float acc[PS * STRIDE];
    int p = blockIdx.x >> 3;          // / SLICES
    int sl = blockIdx.x & (SLICES - 1);
    int tid = threadIdx.x;
    for (int i = tid; i < PS * STRIDE; i += TPB) acc[i] = 0.0f;
    __syncthreads();
    unsigned bs = binStart[p], cnt = binTotal[p];
    unsigned lo = bs + (unsigned)(((unsigned long long)cnt * sl) / SLICES);
    unsigned hi = bs + (unsigned)(((unsigned long long)cnt * (sl + 1)) / SLICES);
    int base = p * PS;
    int g = tid >> 2;                 // 256 groups of 4 lanes
    int lj = tid & 3;
    const unsigned G = TPB / 4;       // 256
    const uint4v* recv = (const uint4v*)records;
    const float4* aux4 = (const float4*)auxT;
    int bb = lj * 4;

    for (unsigned r = lo + g; r < hi; r += G) {
        uint4v rec = __builtin_nontemporal_load(&recv[r]);
        int s = (int)(rec.x & 0xFFFFu);
        int d = (int)(rec.x >> 16);
        float4 vs = aux4[s * 4 + lj];
        float4 vd = aux4[d * 4 + lj];
        float a = __uint_as_float(rec.y);
        float w = __uint_as_float(rec.z);
        float c = __uint_as_float(rec.w);
        float st0 = a * fast_tanh(w * (vs.x - vd.x) + c);
        float st1 = a * fast_tanh(w * (vs.y - vd.y) + c);
        float st2 = a * fast_tanh(w * (vs.z - vd.z) + c);
        float st3 = a * fast_tanh(w * (vs.w - vd.w) + c);
        unsigned ls = (unsigned)(s - base), ld = (unsigned)(d - base);
        if (ls < PS) {
            float* as_ = &acc[ls * STRIDE + bb];
            atomicAdd(as_ + 0, -st0);
            atomicAdd(as_ + 1, -st1);
            atomicAdd(as_ + 2, -st2);
            atomicAdd(as_ + 3, -st3);
        }
        if (ld < PS) {
            float* ad_ = &acc[ld * STRIDE + bb];
            atomicAdd(ad_ + 0, st0);
            atomicAdd(ad_ + 1, st1);
            atomicAdd(ad_ + 2, st2);
            atomicAdd(ad_ + 3, st3);
        }
    }
    __syncthreads();
    float* myPart = partials + (size_t)blockIdx.x * (PS * BATCH);
    for (int i = tid; i < PS * BATCH; i += TPB)
        myPart[i] = acc[(i >> 4) * STRIDE + (i & 15)];
}

// out[b][j] = sum_sl partials[p*SLICES+sl][local*16+b], node i=j+1
__global__ void reduce_sorted(const float* __restrict__ partials,
                              float* __restrict__ out, int n) {
    int idx = blockIdx.x * blockDim.x + threadIdx.x;
    if (idx >= BATCH * n) return;
    int b = idx / n;
    int j = idx % n;
    int i = j + 1;
    int p = i / PS;
    int local = i - p * PS;
    const float* basep = partials + (size_t)p * SLICES * (PS * BATCH)
                         + (size_t)local * BATCH + b;
    float sum = 0.0f;
#pragma unroll
    for (int sl = 0; sl < SLICES; ++sl) sum += basep[(size_t)sl * (PS * BATCH)];
    out[idx] = sum;
}

// ---------------- fallback: direct device atomics ----------------
__global__ void edge_direct(const float* __restrict__ param,
                            const int* __restrict__ src,
                            const int* __restrict__ des,
                            const float* __restrict__ x,
                            float* __restrict__ out, int E, int n) {
    int e = blockIdx.x * blockDim.x + threadIdx.x;
    if (e >= E) return;
    float a = param[e], w = param[E + e], c = param[2 * E + e];
    int s = src[e], d = des[e];
#pragma unroll
    for (int b = 0; b < BATCH; ++b) {
        float vs = s ? x[(size_t)b * n + (s - 1)] : 0.0f;
        float vd = d ? x[(size_t)b * n + (d - 1)] : 0.0f;
        float st = a * tanhf(w * (vs - vd) + c);
        if (s) atomicAdd(out + (size_t)b * n + (s - 1), -st);
        if (d) atomicAdd(out + (size_t)b * n + (d - 1), st);
    }
}

extern "C" void kernel_launch(void* const* d_in, const int* in_sizes, int n_in,
                              void* d_out, int out_size, void* d_ws, size_t ws_size,
                              hipStream_t stream) {
    const float* x     = (const float*)d_in[1];
    const float* param = (const float*)d_in[2];
    const int*   src   = (const int*)d_in[3];
    const int*   des   = (const int*)d_in[4];
    float* out = (float*)d_out;

    int E = in_sizes[3];
    int n = in_sizes[1] / BATCH;   // N = 50000
    int total = BATCH * n;

    auto alignup = [](size_t v) { return (v + 255) & ~(size_t)255; };
    size_t auxBytes   = alignup((size_t)(n + 1) * BATCH * sizeof(float));
    size_t recBytes   = alignup((size_t)2 * E * sizeof(uint4));
    size_t pairBytes  = alignup((size_t)SB * PAIRS * sizeof(unsigned));
    size_t bsBytes    = alignup((size_t)PAIRS * sizeof(unsigned));
    size_t ownBytes   = alignup((size_t)NPART * sizeof(unsigned));
    size_t partBytes  = alignup((size_t)NB * PS * BATCH * sizeof(float));
    size_t needPair   = auxBytes + recBytes + pairBytes + 2 * bsBytes + 2 * ownBytes + partBytes;

    if (ws_size >= needPair && (n + 1) <= NPART * PS && n <= 65535) {
        char* w = (char*)d_ws;
        float*    auxT      = (float*)w;     w += auxBytes;
        uint4*    records   = (uint4*)w;     w += recBytes;
        unsigned* pairHist  = (unsigned*)w;  w += pairBytes;
        unsigned* binStart  = (unsigned*)w;  w += bsBytes;
        unsigned* binTotal  = (unsigned*)w;  w += bsBytes;
        unsigned* ownerStart= (unsigned*)w;  w += ownBytes;
        unsigned* ownerTotal= (unsigned*)w;  w += ownBytes;
        float*    partials  = (float*)w;

        build_aux_T<<<(total + 255) / 256, 256, 0, stream>>>(x, auxT, n);
        pair_hist<<<SB, TPB, 0, stream>>>(src, des, pairHist, E);
        totals_kernel<<<PAIRS / 64, TPB, 0, stream>>>(pairHist, binTotal);
        scan_totals<<<1, 1024, 0, stream>>>(binTotal, binStart, ownerStart, ownerTotal);
        offsets_kernel<<<PAIRS / 64, TPB, 0, stream>>>(pairHist, binStart);
        scatter_pair<<<SB, TPB, 0, stream>>>(src, des, param, pairHist, records, E);
        accumulate_kernel<<<NB, TPB, 0, stream>>>(records, auxT, ownerStart, ownerTotal, partials);
        reduce_sorted<<<(total + 255) / 256, 256, 0, stream>>>(partials, out, n);
        return;
    }

    (void)hipMemsetAsync(out, 0, (size_t)out_size * sizeof(float), stream);
    edge_direct<<<(E + 255) / 256, 256, 0, stream>>>(param, src, des, x, out, E, n);
}